// Round 6
// baseline (93.457 us; speedup 1.0000x reference)
//
#include <hip/hip_runtime.h>

// LocallyConnected2d: x(16,3,128,128) f32, W(61,61,64,3,8,8) f32, bias(64,61,61) f32
// out(16,1,488,488) f32; stride 2, kernel 8, no pad; pixel-shuffle r=8 epilogue.
//
// R5: maximize block TLP. 4 blocks per hw (16 ocs each): LDS = 12 KB W + 12 KB
// x = 24 KB -> 6 blocks/CU, 24 waves/CU. Simple serial {load -> sync ->
// compute} per block; 6-deep cross-block overlap hides load latency.
// Mapping: lane=(q in [0,4) oc-quad, kh in [0,16) K-16th), wave=batch-quad;
// thread owns acc[4oc][4b] over 3 float4. W LDS rows rotation-swizzled with
// slot=(k4+2q) mod 48 (pre-rotated global source): within each 8-lane batch
// (2 kh x 4 q) addresses tile all 8 bank-groups -> conflict-free b128 reads.
// K-combine: shfl_xor 4/8/16/32; kh<4 lanes store batch bq*4+kh.

namespace {
constexpr int NHW  = 61 * 61;       // 3721
constexpr int Kd   = 192;           // 3*8*8
constexpr int XB   = 3 * 128 * 128;
constexpr int XCC  = 128 * 128;
constexpr int OSTR = 488 * 488;
}

__global__ __launch_bounds__(256, 6) void lc2d_kernel(
    const float* __restrict__ xg,   // [16][3][128][128]
    const float* __restrict__ wg,   // [61][61][64][3][8][8]
    const float* __restrict__ bg,   // [64][61][61]
    float* __restrict__ og)         // [16][488][488]
{
    __shared__ float4 wl[16 * 48];                 // 12 KB, rotated rows
    __shared__ __align__(16) float xl[16 * Kd];    // 12 KB, linear [b][k]

    const int bid  = blockIdx.x;
    const int hw   = bid >> 2;
    const int qblk = bid & 3;      // which 16-oc quarter
    const int h    = hw / 61;
    const int w    = hw - h * 61;
    const int t    = threadIdx.x;
    const int lane = t & 63;
    const int wv   = t >> 6;

    // ---- W staging (12 KB): coalesced global_load_lds(16B), pre-rotated src.
    // LDS slot (ocl, s) holds W[ocl][k4], k4 = (s - 2*(ocl>>2)) mod 48.
    {
        const float* wbase = wg + (size_t)hw * (64 * Kd) + qblk * (16 * Kd);
        #pragma unroll
        for (int ci = 0; ci < 3; ++ci) {
            const int s   = wv * 192 + ci * 64 + lane;   // f4 slot 0..767
            const int ocl = s / 48;
            const int t4  = s - ocl * 48;
            int k4 = t4 - 2 * (ocl >> 2);
            if (k4 < 0) k4 += 48;
            __builtin_amdgcn_global_load_lds(
                (const __attribute__((address_space(1))) void*)(wbase + (ocl * 48 + k4) * 4),
                (__attribute__((address_space(3))) void*)&wl[wv * 192 + ci * 64],
                16, 0, 0);
        }
    }
    // ---- x staging (12 KB): manual float2 (validated R0/R1/R4 mapping)
    {
        const float* xbase = xg + (h * 2) * 128 + (w * 2);
        #pragma unroll
        for (int ci = 0; ci < 6; ++ci) {
            const int f  = ci * 256 + t;     // float2 slot 0..1535
            const int b  = f / 96;
            const int r  = f - b * 96;
            const int c  = r >> 5;
            const int r2 = r & 31;
            const int i  = r2 >> 2;
            const int j0 = (r2 & 3) * 2;
            const float2 v = *reinterpret_cast<const float2*>(
                xbase + b * XB + c * XCC + i * 128 + j0);
            *reinterpret_cast<float2*>(&xl[b * Kd + c * 64 + i * 8 + j0]) = v;
        }
    }

    const int q  = lane & 3;    // oc quad within the 16-oc quarter
    const int kh = lane >> 2;   // K 16th (3 float4)
    const int bq = wv;          // batch quad

    // bias for my 4 ocs (L2-resident; issued before the sync)
    float bz[4];
    #pragma unroll
    for (int j = 0; j < 4; ++j)
        bz[j] = bg[(qblk * 16 + q * 4 + j) * NHW + hw];

    __syncthreads();

    float acc[4][4];   // [j(oc)][bb(batch in quad)]
    #pragma unroll
    for (int j = 0; j < 4; ++j)
        #pragma unroll
        for (int bb = 0; bb < 4; ++bb) acc[j][bb] = 0.f;

    #pragma unroll
    for (int kk = 0; kk < 3; ++kk) {
        const int slog = kh * 3 + kk;        // logical f4 index in the row
        int s4 = slog + 2 * q;               // rotation swizzle (rot = 2q)
        if (s4 >= 48) s4 -= 48;
        float4 wv4[4];
        #pragma unroll
        for (int j = 0; j < 4; ++j)
            wv4[j] = wl[(q * 4 + j) * 48 + s4];
        #pragma unroll
        for (int bb = 0; bb < 4; ++bb) {
            const float4 xv = *reinterpret_cast<const float4*>(
                &xl[(bq * 4 + bb) * Kd + slog * 4]);
            #pragma unroll
            for (int j = 0; j < 4; ++j) {
                acc[j][bb] = fmaf(wv4[j].x, xv.x, acc[j][bb]);
                acc[j][bb] = fmaf(wv4[j].y, xv.y, acc[j][bb]);
                acc[j][bb] = fmaf(wv4[j].z, xv.z, acc[j][bb]);
                acc[j][bb] = fmaf(wv4[j].w, xv.w, acc[j][bb]);
            }
        }
    }

    // ---- K-combine over kh (lane bits 2..5 -> xor 4/8/16/32)
    #pragma unroll
    for (int j = 0; j < 4; ++j)
        #pragma unroll
        for (int bb = 0; bb < 4; ++bb) {
            acc[j][bb] += __shfl_xor(acc[j][bb], 4);
            acc[j][bb] += __shfl_xor(acc[j][bb], 8);
            acc[j][bb] += __shfl_xor(acc[j][bb], 16);
            acc[j][bb] += __shfl_xor(acc[j][bb], 32);
        }

    // static select of batch column kh (no runtime array index)
    float colj[4];
    #pragma unroll
    for (int j = 0; j < 4; ++j) {
        float v = acc[j][0];
        v = (kh == 1) ? acc[j][1] : v;
        v = (kh == 2) ? acc[j][2] : v;
        v = (kh == 3) ? acc[j][3] : v;
        colj[j] = v;
    }

    // ---- store: kh<4 lanes store batch bq*4+kh as float4 over the oc quad
    if (kh < 4) {
        const int b    = bq * 4 + kh;
        const int orow = h * 8 + qblk * 2 + (q >> 1);
        const int ocol = w * 8 + (q & 1) * 4;
        float4 ov;
        ov.x = colj[0] + bz[0];
        ov.y = colj[1] + bz[1];
        ov.z = colj[2] + bz[2];
        ov.w = colj[3] + bz[3];
        *reinterpret_cast<float4*>(og + (size_t)b * OSTR + orow * 488 + ocol) = ov;
    }
}

extern "C" void kernel_launch(void* const* d_in, const int* in_sizes, int n_in,
                              void* d_out, int out_size, void* d_ws, size_t ws_size,
                              hipStream_t stream) {
    const float* x    = (const float*)d_in[0];
    const float* W    = (const float*)d_in[1];
    const float* bias = (const float*)d_in[2];
    float* out        = (float*)d_out;
    lc2d_kernel<<<dim3(NHW * 4), dim3(256), 0, stream>>>(x, W, bias, out);
}

// Round 8
// 44.215 us; speedup vs baseline: 2.1137x; 2.1137x over previous
//
#include <hip/hip_runtime.h>

// LocallyConnected2d: x(16,3,128,128) f32, W(61,61,64,3,8,8) f32, bias(64,61,61) f32
// out(16,1,488,488) f32; stride 2, kernel 8, no pad; pixel-shuffle r=8 epilogue.
//
// R6b: MFMA f16 (R6 with the cvt_pkrtz type fix). Per hw: C[16b x 64oc] =
// X[16x192] . W[64x192]^T via mfma_f32_16x16x32_f16 (f32 accumulate).
// Block = 128 thr (2 waves) covers 32 ocs of one hw; wave = one 16-oc n-tile,
// 6 k-steps -> 6 MFMA, zero shuffles. W and x staged as f16 (reg ->
// cvt_pkrtz -> LDS), rows rotation-swizzled (slot=(s8+row&7)%24) so fragment
// ds_read_b128 is 2-way (= free) instead of 16-way. LDS 18 KB -> 8 blocks/CU.
// A-frag: lane holds X[b=lane&15][k=(lane>>4)*8+j]; B-frag: W[oc=lane&15
// row][same k-run]; C: row(batch)=(lane>>4)*4+reg, col(oc)=lane&15.

namespace {
constexpr int NHW  = 61 * 61;       // 3721
constexpr int XB   = 3 * 128 * 128;
constexpr int XCC  = 128 * 128;
constexpr int OSTR = 488 * 488;
}

typedef __fp16   fp16x2 __attribute__((ext_vector_type(2)));
typedef _Float16 half8v __attribute__((ext_vector_type(8)));
typedef float    f32x4  __attribute__((ext_vector_type(4)));

union H8 { fp16x2 p[4]; half8v h; uint4 u; };

__global__ __launch_bounds__(128, 4) void lc2d_kernel(
    const float* __restrict__ xg,   // [16][3][128][128]
    const float* __restrict__ wg,   // [61][61][64][3][8][8]
    const float* __restrict__ bg,   // [64][61][61]
    float* __restrict__ og)         // [16][488][488]
{
    // rows of 192 f16 = 24 slots of 8; slot s8 stored at (s8 + row&7) % 24
    __shared__ __align__(16) _Float16 wlh[32 * 192];   // 12 KB
    __shared__ __align__(16) _Float16 xlh[16 * 192];   //  6 KB

    const int bid  = blockIdx.x;
    const int hw   = bid >> 1;
    const int half = bid & 1;       // which 32-oc half
    const int h    = hw / 61;
    const int w    = hw - h * 61;
    const int t    = threadIdx.x;
    const int lane = t & 63;
    const int wv   = t >> 6;

    // ---- W staging: 6144 f32 -> f16. Thread handles 6 groups of 8 floats.
    {
        const float* wbase = wg + ((size_t)hw * 64 + half * 32) * 192;
        #pragma unroll
        for (int it = 0; it < 6; ++it) {
            const int g  = it * 128 + t;        // f8 group 0..767
            const int oc = g / 24;
            const int s8 = g - oc * 24;
            const float* src = wbase + oc * 192 + s8 * 8;
            const float4 va = *reinterpret_cast<const float4*>(src);
            const float4 vb = *reinterpret_cast<const float4*>(src + 4);
            H8 u;
            u.p[0] = __builtin_amdgcn_cvt_pkrtz(va.x, va.y);
            u.p[1] = __builtin_amdgcn_cvt_pkrtz(va.z, va.w);
            u.p[2] = __builtin_amdgcn_cvt_pkrtz(vb.x, vb.y);
            u.p[3] = __builtin_amdgcn_cvt_pkrtz(vb.z, vb.w);
            int srot = s8 + (oc & 7); if (srot >= 24) srot -= 24;
            *reinterpret_cast<uint4*>(&wlh[oc * 192 + srot * 8]) = u.u;
        }
    }
    // ---- x staging: 3072 f32 -> f16. Thread handles 3 groups of 8 floats.
    {
        const float* xb = xg + (h * 2) * 128 + (w * 2);
        #pragma unroll
        for (int it = 0; it < 3; ++it) {
            const int g  = it * 128 + t;        // f8 group 0..383
            const int b  = g / 24;
            const int s8 = g - b * 24;
            const int c  = s8 >> 3;             // channel
            const int i  = s8 & 7;              // kernel row
            const float* src = xb + b * XB + c * XCC + i * 128;
            const float2 e0 = *reinterpret_cast<const float2*>(src);
            const float2 e1 = *reinterpret_cast<const float2*>(src + 2);
            const float2 e2 = *reinterpret_cast<const float2*>(src + 4);
            const float2 e3 = *reinterpret_cast<const float2*>(src + 6);
            H8 u;
            u.p[0] = __builtin_amdgcn_cvt_pkrtz(e0.x, e0.y);
            u.p[1] = __builtin_amdgcn_cvt_pkrtz(e1.x, e1.y);
            u.p[2] = __builtin_amdgcn_cvt_pkrtz(e2.x, e2.y);
            u.p[3] = __builtin_amdgcn_cvt_pkrtz(e3.x, e3.y);
            int srot = s8 + (b & 7); if (srot >= 24) srot -= 24;
            *reinterpret_cast<uint4*>(&xlh[b * 192 + srot * 8]) = u.u;
        }
    }
    __syncthreads();

    // ---- compute: wave wv handles ocs [half*32 + wv*16, +16)
    const int lq  = lane & 15;          // A row (batch) / B row (oc)
    const int lk  = lane >> 4;          // k-run selector
    const int ocl = wv * 16 + lq;       // row in wlh

    f32x4 acc = {0.f, 0.f, 0.f, 0.f};
    #pragma unroll
    for (int ks = 0; ks < 6; ++ks) {
        const int slog = ks * 4 + lk;
        int sa = slog + (lq & 7);  if (sa >= 24) sa -= 24;
        int sb = slog + (ocl & 7); if (sb >= 24) sb -= 24;
        const half8v av = *reinterpret_cast<const half8v*>(&xlh[lq  * 192 + sa * 8]);
        const half8v bv = *reinterpret_cast<const half8v*>(&wlh[ocl * 192 + sb * 8]);
        acc = __builtin_amdgcn_mfma_f32_16x16x32_f16(av, bv, acc, 0, 0, 0);
    }

    // ---- epilogue: bias + pixel-shuffle store.
    const int   ocg = half * 32 + ocl;
    const float bz  = bg[ocg * NHW + hw];
    float* ob = og + (h * 8 + (ocg >> 3)) * 488 + (w * 8 + (ocg & 7));
    #pragma unroll
    for (int r = 0; r < 4; ++r) {
        const int b = lk * 4 + r;       // batch = C row
        ob[(size_t)b * OSTR] = acc[r] + bz;
    }
}

extern "C" void kernel_launch(void* const* d_in, const int* in_sizes, int n_in,
                              void* d_out, int out_size, void* d_ws, size_t ws_size,
                              hipStream_t stream) {
    const float* x    = (const float*)d_in[0];
    const float* W    = (const float*)d_in[1];
    const float* bias = (const float*)d_in[2];
    float* out        = (float*)d_out;
    lc2d_kernel<<<dim3(NHW * 2), dim3(128), 0, stream>>>(x, W, bias, out);
}